// Round 1
// baseline (36.059 us; speedup 1.0000x reference)
//
#include <hip/hip_runtime.h>

namespace {
constexpr int W = 512, H = 512, D = 8, B = 4;
constexpr int HW  = H * W;
constexpr int DHW = D * HW;
constexpr long YBASE = (long)B * 3 * DHW;  // coords_max elements before y_max
typedef float f32x2 __attribute__((ext_vector_type(2)));
}

struct Row3 {               // one y-row across the 3 z-slabs, x0-1..x0+2
  f32x2 a, b, c;            // aligned float2 at x0 for z-1, z, z+1
  float la, ra, lb, rb, lc, rc;  // clamped halos
};

// x=2-per-lane variant: window 3x3x4 (36 VGPR) + 12-reg prefetch fits the
// 128-VGPR cap -> __launch_bounds__(256,4) = 16 waves/CU (vs 12 at x=4/LB3).
// 8192 waves / 4096 resident = EXACTLY 2 full-occupancy batches (the x=4
// kernel's 8192/3072 = 2.67 batches cost ~11% tail idle). 8-row y-march
// amortizes the 3-row prologue: 10 row-fetches per 8 output rows.
__global__ __launch_bounds__(256, 4) void cqi3d(const float* __restrict__ x,
                                                float* __restrict__ out) {
  int t = blockIdx.x * 256 + threadIdx.x;
  int lane = t & 63;
  int wid = t >> 6;                 // 8192 waves
  int quarter = wid & 3;            // x quarter: 0..3 (128 floats each)
  int y0 = ((wid >> 2) & 63) << 3;  // 64 y-groups of 8 rows
  int z  = (wid >> 8) & 7;
  int b  = wid >> 11;
  int x0 = quarter * 128 + lane * 2;

  int zm1 = z > 0 ? z - 1 : 0, zp1 = z < D - 1 ? z + 1 : D - 1;
  const float* sb0 = x + (size_t)b * DHW + (size_t)zm1 * HW + x0;  // z-1
  const float* sb1 = x + (size_t)b * DHW + (size_t)z   * HW + x0;  // z
  const float* sb2 = x + (size_t)b * DHW + (size_t)zp1 * HW + x0;  // z+1
  int xm = (x0 == 0) ? 0 : -1;          // clamped x-1 offset
  int xp = (x0 == W - 2) ? 1 : 2;       // clamped x+2 offset

  float w[3][3][4];  // [yslot][iz][xc], xc covers x0-1 .. x0+2

  auto fetch = [&](int yq) -> Row3 {
    int yc = yq < 0 ? 0 : (yq > H - 1 ? H - 1 : yq);
    const float* p0 = sb0 + (size_t)yc * W;
    const float* p1 = sb1 + (size_t)yc * W;
    const float* p2 = sb2 + (size_t)yc * W;
    Row3 r;
    r.a = *reinterpret_cast<const f32x2*>(p0); r.la = p0[xm]; r.ra = p0[xp];
    r.b = *reinterpret_cast<const f32x2*>(p1); r.lb = p1[xm]; r.rb = p1[xp];
    r.c = *reinterpret_cast<const f32x2*>(p2); r.lc = p2[xm]; r.rc = p2[xp];
    return r;
  };
  auto commit = [&](int slot, const Row3& r) {
    w[slot][0][0] = r.la; w[slot][0][1] = r.a.x; w[slot][0][2] = r.a.y; w[slot][0][3] = r.ra;
    w[slot][1][0] = r.lb; w[slot][1][1] = r.b.x; w[slot][1][2] = r.b.y; w[slot][1][3] = r.rb;
    w[slot][2][0] = r.lc; w[slot][2][1] = r.c.x; w[slot][2][2] = r.c.y; w[slot][2][3] = r.rc;
  };

  { Row3 r = fetch(y0 - 1); commit(0, r); }
  { Row3 r = fetch(y0);     commit(1, r); }
  { Row3 r = fetch(y0 + 1); commit(2, r); }

  float zf = (float)z, xf = (float)x0;
#pragma unroll
  for (int g = 0; g < 8; ++g) {
    int jm = g % 3, jc = (g + 1) % 3, jp = (g + 2) % 3;
    int y = y0 + g;

    Row3 pf;                       // prefetch y+2 BEFORE compute (hides latency)
    if (g < 7) pf = fetch(y + 2);

    const float (&wm)[3][4] = w[jm];  // y-1
    const float (&wc)[3][4] = w[jc];  // y
    const float (&wp)[3][4] = w[jp];  // y+1

    // shared column maxes over the 9 (y,z) rows
    float cm[4];
#pragma unroll
    for (int q = 0; q < 4; ++q) {
      float m0 = fmaxf(fmaxf(wm[0][q], wm[1][q]), wm[2][q]);
      float m1 = fmaxf(fmaxf(wc[0][q], wc[1][q]), wc[2][q]);
      float m2 = fmaxf(fmaxf(wp[0][q], wp[1][q]), wp[2][q]);
      cm[q] = fmaxf(fmaxf(m0, m1), m2);
    }

    float ods[2], odx[2], ody[2], oym[2];
#pragma unroll
    for (int k = 0; k < 2; ++k) {
      float c  = wc[1][k + 1];
      float bx = 0.5f * (wc[1][k + 2] - wc[1][k]);
      float by = 0.5f * (wp[1][k + 1] - wm[1][k + 1]);
      float bs = 0.5f * (wc[2][k + 1] - wc[0][k + 1]);
      float a  = wc[1][k + 2] - 2.0f * c + wc[1][k];        // dxx
      float b_ = wp[1][k + 1] - 2.0f * c + wm[1][k + 1];    // dyy
      float c_ = wc[2][k + 1] - 2.0f * c + wc[0][k + 1];    // dss
      float dxy = wm[1][k] - wm[1][k + 2] - wp[1][k] + wp[1][k + 2];
      float dys = wm[0][k + 1] - wp[0][k + 1] - wm[2][k + 1] + wp[2][k + 1];
      float dxs = wc[0][k] - wc[0][k + 2] - wc[2][k] + wc[2][k + 2];
      float d_ = 0.25f * dxy, f_ = 0.25f * dys, e_ = 0.25f * dxs;

      // adjugate solve of symmetric [[a,d,e],[d,b,f],[e,f,c]]
      float cof0 = b_ * c_ - f_ * f_;
      float cof1 = e_ * f_ - d_ * c_;
      float cof2 = d_ * f_ - e_ * b_;
      float det = a * cof0 - d_ * (d_ * c_ - f_ * e_) + e_ * cof2;
      bool ok = fabsf(det) > 1e-7f;
      float sd = ok ? det : 1.0f;
      float inv = __builtin_amdgcn_rcpf(sd);  // approx rcp; well within threshold
      float sx = (cof0 * bx + cof1 * by + cof2 * bs) * inv;
      float sy = (cof1 * bx + (a * c_ - e_ * e_) * by + (e_ * d_ - a * f_) * bs) * inv;
      float ss = (cof2 * bx + (e_ * d_ - a * f_) * by + (a * b_ - d_ * d_) * bs) * inv;

      float mx = fmaxf(fmaxf(cm[k], cm[k + 1]), cm[k + 2]);
      bool newm = (c == mx) && ok;
      float dxv = newm ? -sx : 0.0f;
      float dyv = newm ? -sy : 0.0f;
      float dsv = newm ? -ss : 0.0f;
      bool over = fmaxf(fmaxf(fabsf(dxv), fabsf(dyv)), fabsf(dsv)) > 0.7f;
      if (over) { dxv = 0.0f; dyv = 0.0f; dsv = 0.0f; }
      float dy_val = 0.5f * (bx * dxv + by * dyv + bs * dsv);
      ods[k] = dsv;
      odx[k] = dxv;
      ody[k] = dyv;
      oym[k] = c + dy_val + (newm ? 10.0f : 0.0f);
    }

    size_t s  = (size_t)z * HW + (size_t)y * W + x0;
    size_t cb = (size_t)b * 3 * DHW + s;
    float yf = (float)y;
    // nontemporal: outputs are never re-read; keep L2/L3 for the input
    f32x2 v0 = { ods[0] + zf, ods[1] + zf };
    f32x2 v1 = { odx[0] + xf, odx[1] + xf + 1.0f };
    f32x2 v2 = { ody[0] + yf, ody[1] + yf };
    f32x2 v3 = { oym[0], oym[1] };
    __builtin_nontemporal_store(v0, reinterpret_cast<f32x2*>(out + cb));
    __builtin_nontemporal_store(v1, reinterpret_cast<f32x2*>(out + cb + DHW));
    __builtin_nontemporal_store(v2, reinterpret_cast<f32x2*>(out + cb + 2 * DHW));
    __builtin_nontemporal_store(v3, reinterpret_cast<f32x2*>(out + YBASE + (size_t)b * DHW + s));

    if (g < 7) commit(jm, pf);  // retire y-1 slot, bring in y+2
  }
}

extern "C" void kernel_launch(void* const* d_in, const int* in_sizes, int n_in,
                              void* d_out, int out_size, void* d_ws, size_t ws_size,
                              hipStream_t stream) {
  const float* x = (const float*)d_in[0];
  float* out = (float*)d_out;
  // 8192 waves: (b,z,ygroup8,quarter) -> 524288 threads
  dim3 grid(2048), block(256);
  hipLaunchKernelGGL(cqi3d, grid, block, 0, stream, x, out);
}

// Round 2
// 34.889 us; speedup vs baseline: 1.0335x; 1.0335x over previous
//
#include <hip/hip_runtime.h>

namespace {
constexpr int W = 512, H = 512, D = 8, B = 4;
constexpr int HW  = H * W;
constexpr int DHW = D * HW;
constexpr long YBASE = (long)B * 3 * DHW;  // coords_max elements before y_max
typedef float f32x4 __attribute__((ext_vector_type(4)));
}

struct Row3 {               // one y-row across the 3 z-slabs, x0-1..x0+4
  f32x4 a, b, c;            // aligned float4 at x0 for z-1, z, z+1
  float la, ra, lb, rb, lc, rc;  // clamped halos
};

// x=4/4-row structure (the proven 34.1us memory profile: 54 loads + 16
// dwordx4 stores per wave) with the register budget reworked to fit the
// 128-VGPR cap of LB(256,4) = 16 waves/CU:
//  - next-row fetch moved AFTER the k-loop (pf no longer live across the
//    solve -> peak pressure drops ~18 regs); TLP at 4 waves/SIMD covers
//    the exposed load latency.
//  - wave-uniform coords readfirstlane'd to SGPRs; loads/stores use
//    uniform 64-bit base + 32-bit per-lane offsets (saddr form).
// 8192 waves / 4096 resident = EXACTLY 2 batches (LB3 was 2.67 -> 11% tail).
__global__ __launch_bounds__(256, 4) void cqi3d(const float* __restrict__ x,
                                                float* __restrict__ out) {
  int t = blockIdx.x * 256 + threadIdx.x;
  int lane = t & 63;
  int wid = t >> 6;              // 8192 waves
  // wave-uniform -> SGPR
  int half = __builtin_amdgcn_readfirstlane(wid & 1);
  int y0   = __builtin_amdgcn_readfirstlane(((wid >> 1) & 127) << 2);
  int z    = __builtin_amdgcn_readfirstlane((wid >> 8) & 7);
  int b    = __builtin_amdgcn_readfirstlane(wid >> 11);
  int x0 = half * 256 + lane * 4;

  int zm1 = z > 0 ? z - 1 : 0, zp1 = z < D - 1 ? z + 1 : D - 1;
  const float* xb = x + (size_t)b * DHW;   // uniform base (SGPR pair)
  int o0 = zm1 * HW + x0;                  // 32-bit per-lane slab offsets
  int o1 = z   * HW + x0;
  int o2 = zp1 * HW + x0;
  int xm = (x0 == 0) ? 0 : -1;          // clamped x-1 offset
  int xp = (x0 == W - 4) ? 3 : 4;       // clamped x+4 offset

  float w[3][3][6];  // [yslot][iz][xc], xc covers x0-1 .. x0+4

  auto fetch = [&](int yq) -> Row3 {
    int yc = yq < 0 ? 0 : (yq > H - 1 ? H - 1 : yq);
    int yw = yc * W;
    const float* p0 = xb + (o0 + yw);
    const float* p1 = xb + (o1 + yw);
    const float* p2 = xb + (o2 + yw);
    Row3 r;
    r.a = *reinterpret_cast<const f32x4*>(p0); r.la = p0[xm]; r.ra = p0[xp];
    r.b = *reinterpret_cast<const f32x4*>(p1); r.lb = p1[xm]; r.rb = p1[xp];
    r.c = *reinterpret_cast<const f32x4*>(p2); r.lc = p2[xm]; r.rc = p2[xp];
    return r;
  };
  auto commit = [&](int slot, const Row3& r) {
    w[slot][0][0] = r.la; w[slot][0][1] = r.a.x; w[slot][0][2] = r.a.y;
    w[slot][0][3] = r.a.z; w[slot][0][4] = r.a.w; w[slot][0][5] = r.ra;
    w[slot][1][0] = r.lb; w[slot][1][1] = r.b.x; w[slot][1][2] = r.b.y;
    w[slot][1][3] = r.b.z; w[slot][1][4] = r.b.w; w[slot][1][5] = r.rb;
    w[slot][2][0] = r.lc; w[slot][2][1] = r.c.x; w[slot][2][2] = r.c.y;
    w[slot][2][3] = r.c.z; w[slot][2][4] = r.c.w; w[slot][2][5] = r.rc;
  };

  { Row3 r = fetch(y0 - 1); commit(0, r); }
  { Row3 r = fetch(y0);     commit(1, r); }
  { Row3 r = fetch(y0 + 1); commit(2, r); }

  // uniform output bases (SGPR pairs)
  float* ob = out + (size_t)b * 3 * DHW + (size_t)z * HW;
  float* yb = out + YBASE + (size_t)b * DHW + (size_t)z * HW;

  float zf = (float)z;
#pragma unroll
  for (int g = 0; g < 4; ++g) {
    int jm = g % 3, jc = (g + 1) % 3, jp = (g + 2) % 3;
    int y = y0 + g;

    const float (&wm)[3][6] = w[jm];  // y-1
    const float (&wc)[3][6] = w[jc];  // y
    const float (&wp)[3][6] = w[jp];  // y+1

    // shared column maxes over the 9 (y,z) rows
    float cm[6];
#pragma unroll
    for (int q = 0; q < 6; ++q) {
      float m0 = fmaxf(fmaxf(wm[0][q], wm[1][q]), wm[2][q]);
      float m1 = fmaxf(fmaxf(wc[0][q], wc[1][q]), wc[2][q]);
      float m2 = fmaxf(fmaxf(wp[0][q], wp[1][q]), wp[2][q]);
      cm[q] = fmaxf(fmaxf(m0, m1), m2);
    }

    float ods[4], odx[4], ody[4], oym[4];
#pragma unroll
    for (int k = 0; k < 4; ++k) {
      float c  = wc[1][k + 1];
      float bx = 0.5f * (wc[1][k + 2] - wc[1][k]);
      float by = 0.5f * (wp[1][k + 1] - wm[1][k + 1]);
      float bs = 0.5f * (wc[2][k + 1] - wc[0][k + 1]);
      float a  = wc[1][k + 2] - 2.0f * c + wc[1][k];        // dxx
      float b_ = wp[1][k + 1] - 2.0f * c + wm[1][k + 1];    // dyy
      float c_ = wc[2][k + 1] - 2.0f * c + wc[0][k + 1];    // dss
      float dxy = wm[1][k] - wm[1][k + 2] - wp[1][k] + wp[1][k + 2];
      float dys = wm[0][k + 1] - wp[0][k + 1] - wm[2][k + 1] + wp[2][k + 1];
      float dxs = wc[0][k] - wc[0][k + 2] - wc[2][k] + wc[2][k + 2];
      float d_ = 0.25f * dxy, f_ = 0.25f * dys, e_ = 0.25f * dxs;

      // adjugate solve of symmetric [[a,d,e],[d,b,f],[e,f,c]]
      float cof0 = b_ * c_ - f_ * f_;
      float cof1 = e_ * f_ - d_ * c_;
      float cof2 = d_ * f_ - e_ * b_;
      float det = a * cof0 - d_ * (d_ * c_ - f_ * e_) + e_ * cof2;
      bool ok = fabsf(det) > 1e-7f;
      float sd = ok ? det : 1.0f;
      float inv = __builtin_amdgcn_rcpf(sd);  // approx rcp; well within threshold
      float sx = (cof0 * bx + cof1 * by + cof2 * bs) * inv;
      float sy = (cof1 * bx + (a * c_ - e_ * e_) * by + (e_ * d_ - a * f_) * bs) * inv;
      float ss = (cof2 * bx + (e_ * d_ - a * f_) * by + (a * b_ - d_ * d_) * bs) * inv;

      float mx = fmaxf(fmaxf(cm[k], cm[k + 1]), cm[k + 2]);
      bool newm = (c == mx) && ok;
      float dxv = newm ? -sx : 0.0f;
      float dyv = newm ? -sy : 0.0f;
      float dsv = newm ? -ss : 0.0f;
      bool over = fmaxf(fmaxf(fabsf(dxv), fabsf(dyv)), fabsf(dsv)) > 0.7f;
      if (over) { dxv = 0.0f; dyv = 0.0f; dsv = 0.0f; }
      float dy_val = 0.5f * (bx * dxv + by * dyv + bs * dsv);
      ods[k] = dsv;
      odx[k] = dxv;
      ody[k] = dyv;
      oym[k] = c + dy_val + (newm ? 10.0f : 0.0f);
    }

    // issue next-row loads AFTER the solve (pf not live across peak pressure);
    // the stores below cover part of the latency, TLP at 16 waves/CU the rest.
    Row3 pf;
    if (g < 3) pf = fetch(y + 2);

    int so = y * W + x0;                 // 32-bit per-lane store offset
    float yf = (float)y, xf = (float)x0;
    // nontemporal: outputs are never re-read; keep L2/L3 for the input
    f32x4 v0 = { ods[0] + zf, ods[1] + zf, ods[2] + zf, ods[3] + zf };
    f32x4 v1 = { odx[0] + xf, odx[1] + xf + 1.0f, odx[2] + xf + 2.0f, odx[3] + xf + 3.0f };
    f32x4 v2 = { ody[0] + yf, ody[1] + yf, ody[2] + yf, ody[3] + yf };
    f32x4 v3 = { oym[0], oym[1], oym[2], oym[3] };
    __builtin_nontemporal_store(v0, reinterpret_cast<f32x4*>(ob + so));
    __builtin_nontemporal_store(v1, reinterpret_cast<f32x4*>(ob + so + DHW));
    __builtin_nontemporal_store(v2, reinterpret_cast<f32x4*>(ob + so + 2 * DHW));
    __builtin_nontemporal_store(v3, reinterpret_cast<f32x4*>(yb + so));

    if (g < 3) commit(jm, pf);  // retire y-1 slot, bring in y+2
  }
}

extern "C" void kernel_launch(void* const* d_in, const int* in_sizes, int n_in,
                              void* d_out, int out_size, void* d_ws, size_t ws_size,
                              hipStream_t stream) {
  const float* x = (const float*)d_in[0];
  float* out = (float*)d_out;
  // 8192 waves: (b,z,ygroup,half) -> 524288 threads
  dim3 grid(2048), block(256);
  hipLaunchKernelGGL(cqi3d, grid, block, 0, stream, x, out);
}